// Round 3
// baseline (9399.346 us; speedup 1.0000x reference)
//
#include <hip/hip_runtime.h>
#include <hip/hip_bf16.h>

// ---------------- common helpers ----------------
typedef __attribute__((ext_vector_type(8))) short short8_t;
typedef __attribute__((ext_vector_type(4))) float f32x4_t;

__device__ __forceinline__ unsigned short f2bf(float f) {
    unsigned u = __float_as_uint(f);
    unsigned r = (u + 0x7FFFu + ((u >> 16) & 1u)) >> 16;
    return (unsigned short)r;
}
__device__ __forceinline__ float bf2f(unsigned short u) {
    return __uint_as_float(((unsigned)u) << 16);
}
__device__ __forceinline__ float bflo(unsigned u) { return __uint_as_float(u << 16); }
__device__ __forceinline__ float bfhi(unsigned u) { return __uint_as_float(u & 0xFFFF0000u); }
__device__ __forceinline__ float sigm(float x) { return 1.f / (1.f + __expf(-x)); }
__device__ __forceinline__ float tanhfast(float x) {
    x = fminf(fmaxf(x, -15.f), 15.f);
    float e = __expf(2.f * x);
    return (e - 1.f) / (e + 1.f);
}

// coherent-point (IF$) data path: sc1 = agent scope, bypasses non-coherent L1/L2
__device__ __forceinline__ void ld4x16_sc1(const void* p0, const void* p1,
                                           const void* p2, const void* p3,
                                           uint4& a, uint4& b, uint4& c, uint4& d) {
    asm volatile(
        "global_load_dwordx4 %0, %4, off sc1\n\t"
        "global_load_dwordx4 %1, %5, off sc1\n\t"
        "global_load_dwordx4 %2, %6, off sc1\n\t"
        "global_load_dwordx4 %3, %7, off sc1\n\t"
        "s_waitcnt vmcnt(0)"
        : "=v"(a), "=v"(b), "=v"(c), "=v"(d)
        : "v"(p0), "v"(p1), "v"(p2), "v"(p3)
        : "memory");
}
__device__ __forceinline__ void st1_sc1(void* p, unsigned v) {
    asm volatile("global_store_dword %0, %1, off sc1" :: "v"(p), "v"(v) : "memory");
}

// dims
#define BATCH 64
#define SEQ 200
#define HID 512
#define G4 2048           // 4*HID
#define NLAB 66
#define START_L 64
#define STOP_L 65
#define KPAD 320          // 300 padded to mult of 64
#define HROW 520          // hl fp32 row stride (512 + 8 pad)

// ---------------- K1: embed gather + max-norm scale -> bf16 A [12800][320] ----------------
__global__ __launch_bounds__(256) void embed_k(const int* __restrict__ data,
                                               const float* __restrict__ emb,
                                               unsigned short* __restrict__ A) {
    int w = threadIdx.x >> 6, l = threadIdx.x & 63;
    int tok = blockIdx.x * 4 + w;
    int s = tok >> 6, b = tok & 63;
    int row = data[b * SEQ + s];
    const float* src = emb + (size_t)row * 300;
    float vals[5];
    float ss = 0.f;
#pragma unroll
    for (int u = 0; u < 5; u++) {
        int e = l + u * 64;
        float v = (e < 300) ? src[e] : 0.f;
        vals[u] = v;
        ss += v * v;
    }
#pragma unroll
    for (int off = 1; off < 64; off <<= 1) ss += __shfl_xor(ss, off);
    float nrm = sqrtf(ss);
    float scale = fminf(1.f, 6.f / fmaxf(nrm, 1e-7f));
    unsigned short* dst = A + (size_t)tok * KPAD;
#pragma unroll
    for (int u = 0; u < 5; u++) {
        int e = l + u * 64;
        dst[e] = (e < 300) ? f2bf(vals[u] * scale) : (unsigned short)0;
    }
}

// ---------------- K2: W_ih fp32[2048][300] -> bf16 [2048][320] ----------------
__global__ void convw_k(const float* __restrict__ W, unsigned short* __restrict__ Wb) {
    int idx = blockIdx.x * blockDim.x + threadIdx.x;
    if (idx < G4 * KPAD) {
        int r = idx / KPAD, k = idx % KPAD;
        Wb[idx] = (k < 300) ? f2bf(W[r * 300 + k]) : (unsigned short)0;
    }
}

// ---------------- K3/K5: MFMA GEMM  C[m][n] = sum_k A[m][k]*B[n][k] ----------------
// MODE 0: x_proj: A=Wihb[2048][320], B=Aemb[12800][320], C=X bf16 [2048][12800]
// MODE 1: feats : A=W_fc fp32[66][512]->bf16, B=HS [12800][512] bf16, C=F fp32 (+bias)
template <int MODE>
__global__ __launch_bounds__(256) void gemm_k(const unsigned short* __restrict__ Abf,
                                              const float* __restrict__ Af32,
                                              const unsigned short* __restrict__ Bbf,
                                              unsigned short* __restrict__ Cbf,
                                              float* __restrict__ Cf32,
                                              const float* __restrict__ bias) {
    constexpr int KTOT = (MODE == 0) ? KPAD : HID;
    constexpr int NKT = KTOT / 64;
    const int bm = (MODE == 0) ? (blockIdx.x & 15) : 0;
    const int bn = (MODE == 0) ? (blockIdx.x >> 4) : blockIdx.x;
    const int m0 = bm * 128, n0 = bn * 128;
    __shared__ unsigned short Al[128 * 72];
    __shared__ unsigned short Bl[128 * 72];
    const int tid = threadIdx.x;
    const int w = tid >> 6, l = tid & 63;
    const int wr = w >> 1, wc = w & 1;
    f32x4_t acc[4][4];
#pragma unroll
    for (int i = 0; i < 4; i++)
#pragma unroll
        for (int j = 0; j < 4; j++) {
            acc[i][j].x = 0.f; acc[i][j].y = 0.f; acc[i][j].z = 0.f; acc[i][j].w = 0.f;
        }

    for (int kt = 0; kt < NKT; kt++) {
        int row = tid >> 1, half = tid & 1;
        int kbase = kt * 64 + half * 32;
        // ---- stage A tile ----
        if constexpr (MODE == 0) {
            const unsigned short* src = Abf + (size_t)(m0 + row) * KPAD + kbase;
#pragma unroll
            for (int q = 0; q < 4; q++)
                *(short8_t*)&Al[row * 72 + half * 32 + q * 8] = *(const short8_t*)(src + q * 8);
        } else {
            if (row < NLAB) {
                const float* src = Af32 + (size_t)row * HID + kbase;
#pragma unroll
                for (int q = 0; q < 4; q++) {
                    short8_t o;
#pragma unroll
                    for (int x = 0; x < 8; x++) o[x] = (short)f2bf(src[q * 8 + x]);
                    *(short8_t*)&Al[row * 72 + half * 32 + q * 8] = o;
                }
            } else {
                short8_t z = {0, 0, 0, 0, 0, 0, 0, 0};
#pragma unroll
                for (int q = 0; q < 4; q++)
                    *(short8_t*)&Al[row * 72 + half * 32 + q * 8] = z;
            }
        }
        // ---- stage B tile (row-major [n][KTOT] for both modes) ----
        {
            const unsigned short* src = Bbf + (size_t)(n0 + row) * KTOT + kbase;
#pragma unroll
            for (int q = 0; q < 4; q++)
                *(short8_t*)&Bl[row * 72 + half * 32 + q * 8] = *(const short8_t*)(src + q * 8);
        }
        __syncthreads();
#pragma unroll
        for (int kk2 = 0; kk2 < 2; kk2++) {
            short8_t af[4], bfv[4];
#pragma unroll
            for (int i = 0; i < 4; i++)
                af[i] = *(const short8_t*)&Al[(wr * 64 + i * 16 + (l & 15)) * 72 + kk2 * 32 + (l >> 4) * 8];
#pragma unroll
            for (int j = 0; j < 4; j++)
                bfv[j] = *(const short8_t*)&Bl[(wc * 64 + j * 16 + (l & 15)) * 72 + kk2 * 32 + (l >> 4) * 8];
#pragma unroll
            for (int i = 0; i < 4; i++)
#pragma unroll
                for (int j = 0; j < 4; j++)
                    acc[i][j] = __builtin_amdgcn_mfma_f32_16x16x32_bf16(af[i], bfv[j], acc[i][j], 0, 0, 0);
        }
        __syncthreads();
    }
#pragma unroll
    for (int i = 0; i < 4; i++)
#pragma unroll
        for (int j = 0; j < 4; j++)
#pragma unroll
            for (int r = 0; r < 4; r++) {
                int m = m0 + wr * 64 + i * 16 + (l >> 4) * 4 + r;
                int n = n0 + wc * 64 + j * 16 + (l & 15);
                float v = acc[i][j][r];
                if constexpr (MODE == 0) {
                    Cbf[(size_t)m * 12800 + n] = f2bf(v);
                } else {
                    if (m < NLAB) {
                        int b = n & 63, s = n >> 6;
                        Cf32[((size_t)b * SEQ + s) * NLAB + m] = v + bias[m];
                    }
                }
            }
}

// ---------------- K4: persistent LSTM, relaxed flag sync + vectorized sc1 exchange ----
// 256 blocks x 256 threads. group g = blockIdx&3 (16 batches), j = blockIdx>>2 (8 h-dims).
// HS layout: [t][g][lb16][k512] bf16  == flat [token = t*64 + g*16+lb][512].
__global__ __launch_bounds__(256, 1) void lstm_k(const float* __restrict__ Whh,
                                                 const float* __restrict__ bvec,
                                                 const unsigned short* __restrict__ X,
                                                 unsigned short* __restrict__ HS,
                                                 unsigned* __restrict__ flags) {
    const int g = blockIdx.x & 3;
    const int j = blockIdx.x >> 2;
    const int bQ = g * 16;
    const int tid = threadIdx.x;
    const int p = tid & 3;            // k-slice (4-way, 128 k each)
    const int rt = (tid >> 2) & 15;   // row pair (16)
    const int bt = tid >> 6;          // wave = batch quad (4)

    __shared__ float hl[16][HROW];    // [local batch][k] fp32, XOR-chunk-swizzled
    __shared__ float gatesl[32][20];
    __shared__ float bias_s[32];

    // ---- load weights into registers as packed bf16: 2 rows x 128 k ----
    unsigned wreg[2][64];
#pragma unroll
    for (int i = 0; i < 2; i++) {
        int lr = rt * 2 + i;
        int gr = ((lr >> 3) << 9) + j * 8 + (lr & 7);
        const float* wrow = Whh + (size_t)gr * HID + p * 4;
#pragma unroll
        for (int u = 0; u < 32; u++) {
            float4 wv = *(const float4*)(wrow + u * 16);
            wreg[i][u * 2] = (unsigned)f2bf(wv.x) | ((unsigned)f2bf(wv.y) << 16);
            wreg[i][u * 2 + 1] = (unsigned)f2bf(wv.z) | ((unsigned)f2bf(wv.w) << 16);
        }
    }
    if (tid < 32) {
        int gr = ((tid >> 3) << 9) + j * 8 + (tid & 7);
        bias_s[tid] = bvec[gr];
    }
    unsigned* gf = flags + g * 64;

    float cpriv = 0.f;
    const int d = tid >> 4;    // elementwise role (tid<128): h-dim 0..7
    const int lb = tid & 15;   // local batch (phase 3)
    const int f_lb = tid >> 4; // fill role: batch row 0..15
    const int f_kc = tid & 15; // fill role: 32-k chunk 0..15

    for (int t = 0; t < SEQ; t++) {
        // ---- prefetch X gates for this step ----
        float xv[4];
        if (tid < 128) {
#pragma unroll
            for (int q = 0; q < 4; q++)
                xv[q] = bf2f(X[(size_t)(q * HID + j * 8 + d) * 12800 + t * BATCH + bQ + lb]);
        }

        // ---- phase 1: h_{t-1} into LDS ----
        if (t == 0) {
            for (int idx = tid; idx < 16 * HROW; idx += 256) ((float*)hl)[idx] = 0.f;
        } else {
            if (tid < 64) {
                while (__hip_atomic_load(&gf[tid], __ATOMIC_RELAXED,
                                         __HIP_MEMORY_SCOPE_AGENT) < (unsigned)t) {
                    __builtin_amdgcn_s_sleep(1);
                }
            }
            __syncthreads();
            // coalesced sc1 loads: thread reads 64B = 32 k-values of batch f_lb
            const unsigned short* hbase = HS + ((size_t)(t - 1) * 4 + g) * 8192;
            const unsigned short* src = hbase + f_lb * 512 + f_kc * 32;
            uint4 gv[4];
            ld4x16_sc1(src, src + 8, src + 16, src + 24, gv[0], gv[1], gv[2], gv[3]);
            // unpack to fp32, swizzled chunk writes (rotated order for bank spread)
            float* hrow = (float*)hl + f_lb * HROW;
#pragma unroll
            for (int s = 0; s < 8; s++) {
                int i = (s + f_kc) & 7;
                int q = i >> 1, half = i & 1;
                unsigned w0 = gv[q][half * 2], w1 = gv[q][half * 2 + 1];
                f32x4_t v4;
                v4.x = bflo(w0); v4.y = bfhi(w0); v4.z = bflo(w1); v4.w = bfhi(w1);
                int chunk = (f_kc * 8 + i) ^ (f_lb & 7);
                *(f32x4_t*)(hrow + chunk * 4) = v4;
            }
        }
        __syncthreads();

        // ---- phase 2: partial dots (2 rows x 4 batches x 128 k) ----
        float acc[2][4];
#pragma unroll
        for (int i = 0; i < 2; i++)
#pragma unroll
            for (int bb = 0; bb < 4; bb++) acc[i][bb] = 0.f;
#pragma unroll
        for (int u = 0; u < 32; u++) {
            f32x4_t hv[4];
#pragma unroll
            for (int bb = 0; bb < 4; bb++) {
                int row = bt * 4 + bb;
                int chunk = (p + u * 4) ^ (row & 7);
                hv[bb] = *(const f32x4_t*)((float*)hl + row * HROW + chunk * 4);
            }
#pragma unroll
            for (int i = 0; i < 2; i++) {
                unsigned w0 = wreg[i][u * 2], w1 = wreg[i][u * 2 + 1];
                float wx = bflo(w0), wy = bfhi(w0), wz = bflo(w1), ww = bfhi(w1);
#pragma unroll
                for (int bb = 0; bb < 4; bb++) {
                    acc[i][bb] += wx * hv[bb].x + wy * hv[bb].y + wz * hv[bb].z +
                                  ww * hv[bb].w;
                }
            }
        }
#pragma unroll
        for (int i = 0; i < 2; i++)
#pragma unroll
            for (int bb = 0; bb < 4; bb++) {
                float a = acc[i][bb];
                a += __shfl_xor(a, 1);
                a += __shfl_xor(a, 2);
                acc[i][bb] = a;
            }
        if (p == 0) {
#pragma unroll
            for (int i = 0; i < 2; i++) {
                float4 gvv;
                gvv.x = acc[i][0]; gvv.y = acc[i][1]; gvv.z = acc[i][2]; gvv.w = acc[i][3];
                *(float4*)&gatesl[rt * 2 + i][bt * 4] = gvv;
            }
        }
        __syncthreads();

        // ---- phase 3: elementwise LSTM cell (tid<128: 8 dims x 16 batches) ----
        if (tid < 128) {
            float pre[4];
#pragma unroll
            for (int q = 0; q < 4; q++)
                pre[q] = gatesl[q * 8 + d][lb] + bias_s[q * 8 + d] + xv[q];
            float ig = sigm(pre[0]);
            float fg = sigm(pre[1]);
            float gg = tanhfast(pre[2]);
            float og = sigm(pre[3]);
            float c = fg * cpriv + ig * gg;
            cpriv = c;
            float h = og * tanhfast(c);
            // pack pairs across adjacent dims (partner lane tid^16), sc1 store
            unsigned short hb = f2bf(h);
            unsigned short hb1 = (unsigned short)__shfl_xor((int)hb, 16);
            if ((d & 1) == 0) {
                unsigned pk = (unsigned)hb | ((unsigned)hb1 << 16);
                unsigned* hout = (unsigned*)(HS + ((size_t)t * 4 + g) * 8192);
                st1_sc1(&hout[lb * 256 + j * 4 + (d >> 1)], pk);
            }
        }
        asm volatile("s_waitcnt vmcnt(0)" ::: "memory");  // drain sc1 stores (per wave)
        __syncthreads();                                   // all waves drained
        if (tid == 0)
            __hip_atomic_store(&gf[j], (unsigned)(t + 1), __ATOMIC_RELAXED,
                               __HIP_MEMORY_SCOPE_AGENT);
    }
}

// ---------------- K6: CRF forward + scores, one block per batch ----------------
__global__ __launch_bounds__(320) void crf_k(const float* __restrict__ F,
                                             const float* __restrict__ trans,
                                             const int* __restrict__ labels,
                                             const int* __restrict__ lengths,
                                             float* __restrict__ out) {
    const int b = blockIdx.x;
    const int tid = threadIdx.x;
    __shared__ float tl[NLAB * NLAB];
    __shared__ float alpha[2][68];
    __shared__ float fbuf[68];
    __shared__ float red[8];
    __shared__ float norm_s;
    for (int i = tid; i < NLAB * NLAB; i += 320) tl[i] = trans[i];
    const int L = lengths[b];
    const int ii = tid >> 2, jq = tid & 3;
    const int j0 = (jq < 2) ? jq * 17 : 34 + (jq - 2) * 16;
    const int jn = (jq < 2) ? 17 : 16;
    if (tid < NLAB) alpha[0][tid] = (tid == START_L) ? 0.f : -10000.f;
    __syncthreads();
    int p = 0;
    for (int t = 0; t < L; t++) {
        if (tid < NLAB) fbuf[tid] = F[((size_t)b * SEQ + t) * NLAB + tid];
        __syncthreads();
        if (ii < NLAB) {
            float v[17];
            float m = -3.0e38f;
#pragma unroll
            for (int u = 0; u < 17; u++) {
                float x = (u < jn) ? tl[ii * NLAB + j0 + u] + alpha[p][j0 + u] : -3.0e38f;
                v[u] = x;
                m = fmaxf(m, x);
            }
            m = fmaxf(m, __shfl_xor(m, 1));
            m = fmaxf(m, __shfl_xor(m, 2));
            float s = 0.f;
#pragma unroll
            for (int u = 0; u < 17; u++) s += __expf(v[u] - m);
            s += __shfl_xor(s, 1);
            s += __shfl_xor(s, 2);
            if (jq == 0) alpha[p ^ 1][ii] = m + __logf(s) + fbuf[ii];
        }
        __syncthreads();
        p ^= 1;
    }
    if (tid < 64) {
        float v0 = alpha[p][tid] + tl[STOP_L * NLAB + tid];
        float v1 = (tid + 64 < NLAB) ? alpha[p][tid + 64] + tl[STOP_L * NLAB + tid + 64] : -3.0e38f;
        float m = fmaxf(v0, v1);
#pragma unroll
        for (int off = 1; off < 64; off <<= 1) m = fmaxf(m, __shfl_xor(m, off));
        float s = __expf(v0 - m) + ((tid + 64 < NLAB) ? __expf(v1 - m) : 0.f);
#pragma unroll
        for (int off = 1; off < 64; off <<= 1) s += __shfl_xor(s, off);
        if (tid == 0) norm_s = m + __logf(s);
    }
    float local = 0.f;
    const int* lab = labels + (size_t)b * SEQ;
    for (int k = tid; k < L; k += 320) {
        int lk = lab[k];
        int prev = (k == 0) ? START_L : lab[k - 1];
        local += tl[lk * NLAB + prev] + F[((size_t)b * SEQ + k) * NLAB + lk];
    }
    if (tid == 0) local += tl[STOP_L * NLAB + lab[L - 1]];
#pragma unroll
    for (int off = 1; off < 64; off <<= 1) local += __shfl_xor(local, off);
    if ((tid & 63) == 0) red[tid >> 6] = local;
    __syncthreads();
    if (tid == 0) {
        float tot = red[0] + red[1] + red[2] + red[3] + red[4];
        out[b] = norm_s - tot;
    }
}

// ---------------- launch ----------------
extern "C" void kernel_launch(void* const* d_in, const int* in_sizes, int n_in,
                              void* d_out, int out_size, void* d_ws, size_t ws_size,
                              hipStream_t stream) {
    const int* data = (const int*)d_in[0];
    const int* lengths = (const int*)d_in[1];
    const int* labels = (const int*)d_in[2];
    const float* emb = (const float*)d_in[3];
    const float* W_ih = (const float*)d_in[4];
    const float* W_hh = (const float*)d_in[5];
    const float* bvec = (const float*)d_in[6];
    const float* W_fc = (const float*)d_in[7];
    const float* b_fc = (const float*)d_in[8];
    const float* trans = (const float*)d_in[9];
    float* out = (float*)d_out;

    // workspace layout (bytes)
    const size_t oA = 0;                 // Aemb bf16 [12800][320]   8,192,000
    const size_t oW = 8192000;           // Wihb bf16 [2048][320]    1,310,720
    const size_t oX = 9502720;           // X bf16 [2048][12800]    52,428,800
    const size_t oHS = 61931520;         // HS bf16 [12800][512]    13,107,200
    const size_t oF = 75038720;          // F fp32 [64][200][66]     3,379,200
    const size_t oC = 78417920;          // flags [4][64] uint           1,024
    const size_t need = 78418944;
    if (ws_size < need) return;

    char* w = (char*)d_ws;
    unsigned short* A = (unsigned short*)(w + oA);
    unsigned short* Wb = (unsigned short*)(w + oW);
    unsigned short* X = (unsigned short*)(w + oX);
    unsigned short* HS = (unsigned short*)(w + oHS);
    float* F = (float*)(w + oF);
    unsigned* flags = (unsigned*)(w + oC);

    hipMemsetAsync(flags, 0, 1024, stream);
    embed_k<<<3200, 256, 0, stream>>>(data, emb, A);
    convw_k<<<2560, 256, 0, stream>>>(W_ih, Wb);
    gemm_k<0><<<1600, 256, 0, stream>>>(Wb, nullptr, A, X, nullptr, nullptr);
    lstm_k<<<256, 256, 0, stream>>>(W_hh, bvec, X, HS, flags);
    gemm_k<1><<<100, 256, 0, stream>>>(nullptr, W_fc, HS, nullptr, F, b_fc);
    crf_k<<<64, 320, 0, stream>>>(F, trans, labels, lengths, out);
}

// Round 4
// 4083.778 us; speedup vs baseline: 2.3016x; 2.3016x over previous
//
#include <hip/hip_runtime.h>
#include <hip/hip_bf16.h>

// ---------------- common helpers ----------------
typedef __attribute__((ext_vector_type(8))) short short8_t;
typedef __attribute__((ext_vector_type(4))) float f32x4_t;

__device__ __forceinline__ unsigned short f2bf(float f) {
    unsigned u = __float_as_uint(f);
    unsigned r = (u + 0x7FFFu + ((u >> 16) & 1u)) >> 16;
    return (unsigned short)r;
}
__device__ __forceinline__ float bf2f(unsigned short u) {
    return __uint_as_float(((unsigned)u) << 16);
}
__device__ __forceinline__ float bflo(unsigned u) { return __uint_as_float(u << 16); }
__device__ __forceinline__ float bfhi(unsigned u) { return __uint_as_float(u & 0xFFFF0000u); }
__device__ __forceinline__ float sigm(float x) { return 1.f / (1.f + __expf(-x)); }
__device__ __forceinline__ float tanhfast(float x) {
    x = fminf(fmaxf(x, -15.f), 15.f);
    float e = __expf(2.f * x);
    return (e - 1.f) / (e + 1.f);
}

// coherence-point (IF$) data path: sc1 bypasses non-coherent L1/L2
__device__ __forceinline__ void ld4x16_sc1(const void* p0, const void* p1,
                                           const void* p2, const void* p3,
                                           uint4& a, uint4& b, uint4& c, uint4& d) {
    asm volatile(
        "global_load_dwordx4 %0, %4, off sc1\n\t"
        "global_load_dwordx4 %1, %5, off sc1\n\t"
        "global_load_dwordx4 %2, %6, off sc1\n\t"
        "global_load_dwordx4 %3, %7, off sc1\n\t"
        "s_waitcnt vmcnt(0)"
        : "=v"(a), "=v"(b), "=v"(c), "=v"(d)
        : "v"(p0), "v"(p1), "v"(p2), "v"(p3)
        : "memory");
}
__device__ __forceinline__ void st1_sc1(void* p, unsigned v) {
    asm volatile("global_store_dword %0, %1, off sc1" :: "v"(p), "v"(v) : "memory");
}
__device__ __forceinline__ unsigned ld1_sc1(const void* p) {
    unsigned v;
    asm volatile("global_load_dword %0, %1, off sc1\n\ts_waitcnt vmcnt(0)"
                 : "=v"(v) : "v"(p) : "memory");
    return v;
}

// dims
#define BATCH 64
#define SEQ 200
#define HID 512
#define G4 2048           // 4*HID
#define NLAB 66
#define START_L 64
#define STOP_L 65
#define KPAD 320          // 300 padded to mult of 64
#define HROW 520          // hl fp32 row stride (512 + 8 pad)

// HS segmented layout: per (t, g): 64 segments (one per j-block) of 64 dwords.
//   seg (t,g,j) dword r = (d>>1)*16 + lb holds bf16 pair (k=j*8+d [lo], k+1 [hi]) for batch g*16+lb.

// ---------------- K1: embed gather + max-norm scale -> bf16 A [12800][320] ----------------
__global__ __launch_bounds__(256) void embed_k(const int* __restrict__ data,
                                               const float* __restrict__ emb,
                                               unsigned short* __restrict__ A) {
    int w = threadIdx.x >> 6, l = threadIdx.x & 63;
    int tok = blockIdx.x * 4 + w;
    int s = tok >> 6, b = tok & 63;
    int row = data[b * SEQ + s];
    const float* src = emb + (size_t)row * 300;
    float vals[5];
    float ss = 0.f;
#pragma unroll
    for (int u = 0; u < 5; u++) {
        int e = l + u * 64;
        float v = (e < 300) ? src[e] : 0.f;
        vals[u] = v;
        ss += v * v;
    }
#pragma unroll
    for (int off = 1; off < 64; off <<= 1) ss += __shfl_xor(ss, off);
    float nrm = sqrtf(ss);
    float scale = fminf(1.f, 6.f / fmaxf(nrm, 1e-7f));
    unsigned short* dst = A + (size_t)tok * KPAD;
#pragma unroll
    for (int u = 0; u < 5; u++) {
        int e = l + u * 64;
        dst[e] = (e < 300) ? f2bf(vals[u] * scale) : (unsigned short)0;
    }
}

// ---------------- K2: W_ih fp32[2048][300] -> bf16 [2048][320] ----------------
__global__ void convw_k(const float* __restrict__ W, unsigned short* __restrict__ Wb) {
    int idx = blockIdx.x * blockDim.x + threadIdx.x;
    if (idx < G4 * KPAD) {
        int r = idx / KPAD, k = idx % KPAD;
        Wb[idx] = (k < 300) ? f2bf(W[r * 300 + k]) : (unsigned short)0;
    }
}

// ---------------- K3/K5: MFMA GEMM  C[m][n] = sum_k A[m][k]*B[n][k] ----------------
// MODE 0: x_proj: A=Wihb[2048][320], B=Aemb[12800][320], C=X bf16 [2048][12800]
// MODE 1: feats : A=W_fc fp32[66][512]->bf16, B=HS segmented (decoded), C=F fp32 (+bias)
template <int MODE>
__global__ __launch_bounds__(256) void gemm_k(const unsigned short* __restrict__ Abf,
                                              const float* __restrict__ Af32,
                                              const unsigned short* __restrict__ Bbf,
                                              unsigned short* __restrict__ Cbf,
                                              float* __restrict__ Cf32,
                                              const float* __restrict__ bias) {
    constexpr int KTOT = (MODE == 0) ? KPAD : HID;
    constexpr int NKT = KTOT / 64;
    const int bm = (MODE == 0) ? (blockIdx.x & 15) : 0;
    const int bn = (MODE == 0) ? (blockIdx.x >> 4) : blockIdx.x;
    const int m0 = bm * 128, n0 = bn * 128;
    __shared__ unsigned short Al[128 * 72];
    __shared__ unsigned short Bl[128 * 72];
    const int tid = threadIdx.x;
    const int w = tid >> 6, l = tid & 63;
    const int wr = w >> 1, wc = w & 1;
    f32x4_t acc[4][4];
#pragma unroll
    for (int i = 0; i < 4; i++)
#pragma unroll
        for (int j = 0; j < 4; j++) {
            acc[i][j].x = 0.f; acc[i][j].y = 0.f; acc[i][j].z = 0.f; acc[i][j].w = 0.f;
        }

    for (int kt = 0; kt < NKT; kt++) {
        int row = tid >> 1, half = tid & 1;
        int kbase = kt * 64 + half * 32;
        // ---- stage A tile ----
        if constexpr (MODE == 0) {
            const unsigned short* src = Abf + (size_t)(m0 + row) * KPAD + kbase;
#pragma unroll
            for (int q = 0; q < 4; q++)
                *(short8_t*)&Al[row * 72 + half * 32 + q * 8] = *(const short8_t*)(src + q * 8);
        } else {
            if (row < NLAB) {
                const float* src = Af32 + (size_t)row * HID + kbase;
#pragma unroll
                for (int q = 0; q < 4; q++) {
                    short8_t o;
#pragma unroll
                    for (int x = 0; x < 8; x++) o[x] = (short)f2bf(src[q * 8 + x]);
                    *(short8_t*)&Al[row * 72 + half * 32 + q * 8] = o;
                }
            } else {
                short8_t z = {0, 0, 0, 0, 0, 0, 0, 0};
#pragma unroll
                for (int q = 0; q < 4; q++)
                    *(short8_t*)&Al[row * 72 + half * 32 + q * 8] = z;
            }
        }
        // ---- stage B tile ----
        if constexpr (MODE == 0) {
            const unsigned short* src = Bbf + (size_t)(n0 + row) * KTOT + kbase;
#pragma unroll
            for (int q = 0; q < 4; q++)
                *(short8_t*)&Bl[row * 72 + half * 32 + q * 8] = *(const short8_t*)(src + q * 8);
        } else {
            // decode segmented HS: tile = tokens [n0, n0+128) = t in {2bn, 2bn+1}, k chunk kt*64..
            const unsigned* HSu = (const unsigned*)Bbf;
            int t0 = bn * 2, j0 = kt * 8;
            int sj = tid >> 2;                 // 0..63: which seg of the 64 needed
            int jj = sj & 7, gg = (sj >> 3) & 3, tt = sj >> 5;
            int dd = tid & 3;
            const unsigned* src = HSu + ((((size_t)(t0 + tt) * 4 + gg) * 64) + (j0 + jj)) * 64 +
                                  dd * 16;
            uint4 va = *(const uint4*)src;
            uint4 vb = *(const uint4*)(src + 4);
            uint4 vc = *(const uint4*)(src + 8);
            uint4 vd = *(const uint4*)(src + 12);
            int kloc = jj * 8 + dd * 2;
            int rowbase = tt * 64 + gg * 16;
#pragma unroll
            for (int x = 0; x < 16; x++) {
                unsigned pk = (x < 4) ? va[x] : (x < 8) ? vb[x - 4] : (x < 12) ? vc[x - 8]
                                                                               : vd[x - 12];
                *(unsigned*)&Bl[(rowbase + x) * 72 + kloc] = pk;
            }
        }
        __syncthreads();
#pragma unroll
        for (int kk2 = 0; kk2 < 2; kk2++) {
            short8_t af[4], bfv[4];
#pragma unroll
            for (int i = 0; i < 4; i++)
                af[i] = *(const short8_t*)&Al[(wr * 64 + i * 16 + (l & 15)) * 72 + kk2 * 32 + (l >> 4) * 8];
#pragma unroll
            for (int j = 0; j < 4; j++)
                bfv[j] = *(const short8_t*)&Bl[(wc * 64 + j * 16 + (l & 15)) * 72 + kk2 * 32 + (l >> 4) * 8];
#pragma unroll
            for (int i = 0; i < 4; i++)
#pragma unroll
                for (int j = 0; j < 4; j++)
                    acc[i][j] = __builtin_amdgcn_mfma_f32_16x16x32_bf16(af[i], bfv[j], acc[i][j], 0, 0, 0);
        }
        __syncthreads();
    }
#pragma unroll
    for (int i = 0; i < 4; i++)
#pragma unroll
        for (int j = 0; j < 4; j++)
#pragma unroll
            for (int r = 0; r < 4; r++) {
                int m = m0 + wr * 64 + i * 16 + (l >> 4) * 4 + r;
                int n = n0 + wc * 64 + j * 16 + (l & 15);
                float v = acc[i][j][r];
                if constexpr (MODE == 0) {
                    Cbf[(size_t)m * 12800 + n] = f2bf(v);
                } else {
                    if (m < NLAB) {
                        int b = n & 63, s = n >> 6;
                        Cf32[((size_t)b * SEQ + s) * NLAB + m] = v + bias[m];
                    }
                }
            }
}

// ---------------- K4: persistent LSTM ----------------
// 256 blocks x 256 threads. group g = blockIdx&3 (16 batches), j = blockIdx>>2 (8 h-dims).
// Producer writes its 256B segment (2 full lines, sc1); per-producer flags spread over 4 lines,
// polled by wave 0 only with s_sleep(8) throttle.
__global__ __launch_bounds__(256, 1) void lstm_k(const float* __restrict__ Whh,
                                                 const float* __restrict__ bvec,
                                                 const unsigned short* __restrict__ X,
                                                 unsigned short* __restrict__ HS,
                                                 unsigned* __restrict__ flags) {
    const int g = blockIdx.x & 3;
    const int j = blockIdx.x >> 2;
    const int bQ = g * 16;
    const int tid = threadIdx.x;
    const int p = tid & 3;            // k-slice (4-way, 128 k each)
    const int rt = (tid >> 2) & 15;   // row pair (16)
    const int bt = tid >> 6;          // wave = batch quad (4)

    __shared__ float hl[16][HROW];    // [local batch][k] fp32
    __shared__ float gatesl[32][20];
    __shared__ float bias_s[32];

    // ---- load weights into registers as packed bf16: 2 rows x 128 k ----
    unsigned wreg[2][64];
#pragma unroll
    for (int i = 0; i < 2; i++) {
        int lr = rt * 2 + i;
        int gr = ((lr >> 3) << 9) + j * 8 + (lr & 7);
        const float* wrow = Whh + (size_t)gr * HID + p * 4;
#pragma unroll
        for (int u = 0; u < 32; u++) {
            float4 wv = *(const float4*)(wrow + u * 16);
            wreg[i][u * 2] = (unsigned)f2bf(wv.x) | ((unsigned)f2bf(wv.y) << 16);
            wreg[i][u * 2 + 1] = (unsigned)f2bf(wv.z) | ((unsigned)f2bf(wv.w) << 16);
        }
    }
    if (tid < 32) {
        int gr = ((tid >> 3) << 9) + j * 8 + (tid & 7);
        bias_s[tid] = bvec[gr];
    }
    unsigned* gf = flags + g * 128;   // flag j at gf[j*2] (64 flags over 512B = 4 lines)
    unsigned* HSu = (unsigned*)HS;

    float cpriv = 0.f;
    const int d = tid >> 4;    // elementwise role (tid<128): h-dim 0..7
    const int lb = tid & 15;   // local batch (phase 3)

    for (int t = 0; t < SEQ; t++) {
        // ---- prefetch X gates (in flight during poll) ----
        float xv[4];
        if (tid < 128) {
#pragma unroll
            for (int q = 0; q < 4; q++)
                xv[q] = bf2f(X[(size_t)(q * HID + j * 8 + d) * 12800 + t * BATCH + bQ + lb]);
        }

        // ---- phase 1: h_{t-1} into LDS ----
        if (t == 0) {
            for (int idx = tid; idx < 16 * HROW; idx += 256) ((float*)hl)[idx] = 0.f;
        } else {
            if (tid < 64) {
                unsigned v = ld1_sc1(&gf[tid * 2]);
                while (!__all(v >= (unsigned)t)) {
                    __builtin_amdgcn_s_sleep(8);
                    v = ld1_sc1(&gf[tid * 2]);
                }
            }
            __syncthreads();
            // coalesced read of this group's 16 KB (4096 dwords): thread gets 16 dwords
            const unsigned* hsrc = HSu + ((size_t)(t - 1) * 4 + g) * 4096 + tid * 16;
            uint4 va, vb, vc, vd;
            ld4x16_sc1(hsrc, hsrc + 4, hsrc + 8, hsrc + 12, va, vb, vc, vd);
            // decode: seg j' = tid>>2, dd = tid&3, lb' = x  ->  k0 = j'*8 + dd*2
            int k0 = (tid >> 2) * 8 + (tid & 3) * 2;
#pragma unroll
            for (int x = 0; x < 16; x++) {
                unsigned pk = (x < 4) ? va[x] : (x < 8) ? vb[x - 4] : (x < 12) ? vc[x - 8]
                                                                               : vd[x - 12];
                float2 f2;
                f2.x = bflo(pk);
                f2.y = bfhi(pk);
                *(float2*)&hl[x][k0] = f2;
            }
        }
        __syncthreads();

        // ---- phase 2: partial dots (2 rows x 4 batches x 128 k) ----
        float acc[2][4];
#pragma unroll
        for (int i = 0; i < 2; i++)
#pragma unroll
            for (int bb = 0; bb < 4; bb++) acc[i][bb] = 0.f;
#pragma unroll
        for (int u = 0; u < 32; u++) {
            f32x4_t hv[4];
#pragma unroll
            for (int bb = 0; bb < 4; bb++)
                hv[bb] = *(const f32x4_t*)&hl[bt * 4 + bb][u * 16 + p * 4];
#pragma unroll
            for (int i = 0; i < 2; i++) {
                unsigned w0 = wreg[i][u * 2], w1 = wreg[i][u * 2 + 1];
                float wx = bflo(w0), wy = bfhi(w0), wz = bflo(w1), ww = bfhi(w1);
#pragma unroll
                for (int bb = 0; bb < 4; bb++) {
                    acc[i][bb] += wx * hv[bb].x + wy * hv[bb].y + wz * hv[bb].z +
                                  ww * hv[bb].w;
                }
            }
        }
#pragma unroll
        for (int i = 0; i < 2; i++)
#pragma unroll
            for (int bb = 0; bb < 4; bb++) {
                float a = acc[i][bb];
                a += __shfl_xor(a, 1);
                a += __shfl_xor(a, 2);
                acc[i][bb] = a;
            }
        if (p == 0) {
#pragma unroll
            for (int i = 0; i < 2; i++) {
                float4 gvv;
                gvv.x = acc[i][0]; gvv.y = acc[i][1]; gvv.z = acc[i][2]; gvv.w = acc[i][3];
                *(float4*)&gatesl[rt * 2 + i][bt * 4] = gvv;
            }
        }
        __syncthreads();

        // ---- phase 3: elementwise LSTM cell (tid<128: 8 dims x 16 batches) ----
        if (tid < 128) {
            float pre[4];
#pragma unroll
            for (int q = 0; q < 4; q++)
                pre[q] = gatesl[q * 8 + d][lb] + bias_s[q * 8 + d] + xv[q];
            float ig = sigm(pre[0]);
            float fg = sigm(pre[1]);
            float gg = tanhfast(pre[2]);
            float og = sigm(pre[3]);
            float c = fg * cpriv + ig * gg;
            cpriv = c;
            float h = og * tanhfast(c);
            // pack d-pairs (partner lane tid^16), contiguous 256B segment store
            unsigned short hb = f2bf(h);
            unsigned short hb1 = (unsigned short)__shfl_xor((int)hb, 16);
            if ((d & 1) == 0) {
                unsigned pk = (unsigned)hb | ((unsigned)hb1 << 16);
                unsigned* seg = HSu + (((size_t)t * 4 + g) * 64 + j) * 64;
                st1_sc1(&seg[(d >> 1) * 16 + lb], pk);
            }
        }
        asm volatile("s_waitcnt vmcnt(0)" ::: "memory");
        __syncthreads();  // all waves' sc1 stores drained
        if (tid == 0)
            st1_sc1(&gf[j * 2], (unsigned)(t + 1));
    }
}

// ---------------- K6: CRF forward + scores, one block per batch ----------------
__global__ __launch_bounds__(320) void crf_k(const float* __restrict__ F,
                                             const float* __restrict__ trans,
                                             const int* __restrict__ labels,
                                             const int* __restrict__ lengths,
                                             float* __restrict__ out) {
    const int b = blockIdx.x;
    const int tid = threadIdx.x;
    __shared__ float tl[NLAB * NLAB];
    __shared__ float alpha[2][68];
    __shared__ float fbuf[68];
    __shared__ float red[8];
    __shared__ float norm_s;
    for (int i = tid; i < NLAB * NLAB; i += 320) tl[i] = trans[i];
    const int L = lengths[b];
    const int ii = tid >> 2, jq = tid & 3;
    const int j0 = (jq < 2) ? jq * 17 : 34 + (jq - 2) * 16;
    const int jn = (jq < 2) ? 17 : 16;
    if (tid < NLAB) alpha[0][tid] = (tid == START_L) ? 0.f : -10000.f;
    __syncthreads();
    int p = 0;
    for (int t = 0; t < L; t++) {
        if (tid < NLAB) fbuf[tid] = F[((size_t)b * SEQ + t) * NLAB + tid];
        __syncthreads();
        if (ii < NLAB) {
            float v[17];
            float m = -3.0e38f;
#pragma unroll
            for (int u = 0; u < 17; u++) {
                float x = (u < jn) ? tl[ii * NLAB + j0 + u] + alpha[p][j0 + u] : -3.0e38f;
                v[u] = x;
                m = fmaxf(m, x);
            }
            m = fmaxf(m, __shfl_xor(m, 1));
            m = fmaxf(m, __shfl_xor(m, 2));
            float s = 0.f;
#pragma unroll
            for (int u = 0; u < 17; u++) s += __expf(v[u] - m);
            s += __shfl_xor(s, 1);
            s += __shfl_xor(s, 2);
            if (jq == 0) alpha[p ^ 1][ii] = m + __logf(s) + fbuf[ii];
        }
        __syncthreads();
        p ^= 1;
    }
    if (tid < 64) {
        float v0 = alpha[p][tid] + tl[STOP_L * NLAB + tid];
        float v1 = (tid + 64 < NLAB) ? alpha[p][tid + 64] + tl[STOP_L * NLAB + tid + 64] : -3.0e38f;
        float m = fmaxf(v0, v1);
#pragma unroll
        for (int off = 1; off < 64; off <<= 1) m = fmaxf(m, __shfl_xor(m, off));
        float s = __expf(v0 - m) + ((tid + 64 < NLAB) ? __expf(v1 - m) : 0.f);
#pragma unroll
        for (int off = 1; off < 64; off <<= 1) s += __shfl_xor(s, off);
        if (tid == 0) norm_s = m + __logf(s);
    }
    float local = 0.f;
    const int* lab = labels + (size_t)b * SEQ;
    for (int k = tid; k < L; k += 320) {
        int lk = lab[k];
        int prev = (k == 0) ? START_L : lab[k - 1];
        local += tl[lk * NLAB + prev] + F[((size_t)b * SEQ + k) * NLAB + lk];
    }
    if (tid == 0) local += tl[STOP_L * NLAB + lab[L - 1]];
#pragma unroll
    for (int off = 1; off < 64; off <<= 1) local += __shfl_xor(local, off);
    if ((tid & 63) == 0) red[tid >> 6] = local;
    __syncthreads();
    if (tid == 0) {
        float tot = red[0] + red[1] + red[2] + red[3] + red[4];
        out[b] = norm_s - tot;
    }
}

// ---------------- launch ----------------
extern "C" void kernel_launch(void* const* d_in, const int* in_sizes, int n_in,
                              void* d_out, int out_size, void* d_ws, size_t ws_size,
                              hipStream_t stream) {
    const int* data = (const int*)d_in[0];
    const int* lengths = (const int*)d_in[1];
    const int* labels = (const int*)d_in[2];
    const float* emb = (const float*)d_in[3];
    const float* W_ih = (const float*)d_in[4];
    const float* W_hh = (const float*)d_in[5];
    const float* bvec = (const float*)d_in[6];
    const float* W_fc = (const float*)d_in[7];
    const float* b_fc = (const float*)d_in[8];
    const float* trans = (const float*)d_in[9];
    float* out = (float*)d_out;

    // workspace layout (bytes)
    const size_t oA = 0;                 // Aemb bf16 [12800][320]   8,192,000
    const size_t oW = 8192000;           // Wihb bf16 [2048][320]    1,310,720
    const size_t oX = 9502720;           // X bf16 [2048][12800]    52,428,800
    const size_t oHS = 61931520;         // HS segmented bf16       13,107,200
    const size_t oF = 75038720;          // F fp32 [64][200][66]     3,379,200
    const size_t oC = 78417920;          // flags [4][128] uint          2,048
    const size_t need = 78419968;
    if (ws_size < need) return;

    char* w = (char*)d_ws;
    unsigned short* A = (unsigned short*)(w + oA);
    unsigned short* Wb = (unsigned short*)(w + oW);
    unsigned short* X = (unsigned short*)(w + oX);
    unsigned short* HS = (unsigned short*)(w + oHS);
    float* F = (float*)(w + oF);
    unsigned* flags = (unsigned*)(w + oC);

    hipMemsetAsync(flags, 0, 2048, stream);
    embed_k<<<3200, 256, 0, stream>>>(data, emb, A);
    convw_k<<<2560, 256, 0, stream>>>(W_ih, Wb);
    gemm_k<0><<<1600, 256, 0, stream>>>(Wb, nullptr, A, X, nullptr, nullptr);
    lstm_k<<<256, 256, 0, stream>>>(W_hh, bvec, X, HS, flags);
    gemm_k<1><<<100, 256, 0, stream>>>(nullptr, W_fc, HS, nullptr, F, b_fc);
    crf_k<<<64, 320, 0, stream>>>(F, trans, labels, lengths, out);
}

// Round 6
// 882.437 us; speedup vs baseline: 10.6516x; 4.6278x over previous
//
#include <hip/hip_runtime.h>
#include <hip/hip_bf16.h>

// ---------------- common helpers ----------------
typedef __attribute__((ext_vector_type(8))) short short8_t;
typedef __attribute__((ext_vector_type(4))) float f32x4_t;

__device__ __forceinline__ unsigned short f2bf(float f) {
    unsigned u = __float_as_uint(f);
    unsigned r = (u + 0x7FFFu + ((u >> 16) & 1u)) >> 16;
    return (unsigned short)r;
}
__device__ __forceinline__ float bf2f(unsigned short u) {
    return __uint_as_float(((unsigned)u) << 16);
}
__device__ __forceinline__ float bflo(unsigned u) { return __uint_as_float(u << 16); }
__device__ __forceinline__ float bfhi(unsigned u) { return __uint_as_float(u & 0xFFFF0000u); }
__device__ __forceinline__ float sigm(float x) { return 1.f / (1.f + __expf(-x)); }
__device__ __forceinline__ float tanhfast(float x) {
    x = fminf(fmaxf(x, -15.f), 15.f);
    float e = __expf(2.f * x);
    return (e - 1.f) / (e + 1.f);
}

// coherence-point (IF$) data path: sc1 bypasses non-coherent L1/L2
__device__ __forceinline__ void ld4_sc1(const void* p, uint4& a) {
    asm volatile("global_load_dwordx4 %0, %1, off sc1\n\ts_waitcnt vmcnt(0)"
                 : "=v"(a) : "v"(p) : "memory");
}
__device__ __forceinline__ void st1_sc1(void* p, unsigned v) {
    asm volatile("global_store_dword %0, %1, off sc1" :: "v"(p), "v"(v) : "memory");
}
__device__ __forceinline__ unsigned ld1_sc1(const void* p) {
    unsigned v;
    asm volatile("global_load_dword %0, %1, off sc1\n\ts_waitcnt vmcnt(0)"
                 : "=v"(v) : "v"(p) : "memory");
    return v;
}

// dims
#define BATCH 64
#define SEQ 200
#define HID 512
#define G4 2048           // 4*HID
#define NLAB 66
#define START_L 64
#define STOP_L 65
#define KPAD 320          // 300 padded to mult of 64

// Decomposition: 8 groups (8 batches each) x 8 blocks (64 h-dims / 256 gate rows each).
// HS layout: per (t,g): 8 segs (one per j) of 64 dims x 8 batches bf16 = 1KB; HS[t][g] = 8KB.
// X  layout: Xr[g][row(2048)][t(200)][lb(8)] bf16 (t-contiguous 16B per step).

// ---------------- K1: embed gather + max-norm scale -> bf16 A [12800][320] ----------------
__global__ __launch_bounds__(256) void embed_k(const int* __restrict__ data,
                                               const float* __restrict__ emb,
                                               unsigned short* __restrict__ A) {
    int w = threadIdx.x >> 6, l = threadIdx.x & 63;
    int tok = blockIdx.x * 4 + w;
    int s = tok >> 6, b = tok & 63;
    int row = data[b * SEQ + s];
    const float* src = emb + (size_t)row * 300;
    float vals[5];
    float ss = 0.f;
#pragma unroll
    for (int u = 0; u < 5; u++) {
        int e = l + u * 64;
        float v = (e < 300) ? src[e] : 0.f;
        vals[u] = v;
        ss += v * v;
    }
#pragma unroll
    for (int off = 1; off < 64; off <<= 1) ss += __shfl_xor(ss, off);
    float nrm = sqrtf(ss);
    float scale = fminf(1.f, 6.f / fmaxf(nrm, 1e-7f));
    unsigned short* dst = A + (size_t)tok * KPAD;
#pragma unroll
    for (int u = 0; u < 5; u++) {
        int e = l + u * 64;
        dst[e] = (e < 300) ? f2bf(vals[u] * scale) : (unsigned short)0;
    }
}

// ---------------- K2: W_ih fp32[2048][300] -> bf16 [2048][320] ----------------
__global__ void convw_k(const float* __restrict__ W, unsigned short* __restrict__ Wb) {
    int idx = blockIdx.x * blockDim.x + threadIdx.x;
    if (idx < G4 * KPAD) {
        int r = idx / KPAD, k = idx % KPAD;
        Wb[idx] = (k < 300) ? f2bf(W[r * 300 + k]) : (unsigned short)0;
    }
}

// ---------------- K3/K5: MFMA GEMM  C[m][n] = sum_k A[m][k]*B[n][k] ----------------
// MODE 0: x_proj: A=Wihb[2048][320], B=Aemb[12800][320], C=X bf16 in Xr layout
// MODE 1: feats : A=W_fc fp32[66][512]->bf16, B=HS segmented (decoded), C=F fp32 (+bias)
template <int MODE>
__global__ __launch_bounds__(256) void gemm_k(const unsigned short* __restrict__ Abf,
                                              const float* __restrict__ Af32,
                                              const unsigned short* __restrict__ Bbf,
                                              unsigned short* __restrict__ Cbf,
                                              float* __restrict__ Cf32,
                                              const float* __restrict__ bias) {
    constexpr int KTOT = (MODE == 0) ? KPAD : HID;
    constexpr int NKT = KTOT / 64;
    const int bm = (MODE == 0) ? (blockIdx.x & 15) : 0;
    const int bn = (MODE == 0) ? (blockIdx.x >> 4) : blockIdx.x;
    const int m0 = bm * 128, n0 = bn * 128;
    __shared__ unsigned short Al[128 * 72];
    __shared__ unsigned short Bl[128 * 72];
    const int tid = threadIdx.x;
    const int w = tid >> 6, l = tid & 63;
    const int wr = w >> 1, wc = w & 1;
    f32x4_t acc[4][4];
#pragma unroll
    for (int i = 0; i < 4; i++)
#pragma unroll
        for (int j = 0; j < 4; j++) {
            acc[i][j].x = 0.f; acc[i][j].y = 0.f; acc[i][j].z = 0.f; acc[i][j].w = 0.f;
        }

    for (int kt = 0; kt < NKT; kt++) {
        int row = tid >> 1, half = tid & 1;
        int kbase = kt * 64 + half * 32;
        // ---- stage A tile ----
        if constexpr (MODE == 0) {
            const unsigned short* src = Abf + (size_t)(m0 + row) * KPAD + kbase;
#pragma unroll
            for (int q = 0; q < 4; q++)
                *(short8_t*)&Al[row * 72 + half * 32 + q * 8] = *(const short8_t*)(src + q * 8);
        } else {
            if (row < NLAB) {
                const float* src = Af32 + (size_t)row * HID + kbase;
#pragma unroll
                for (int q = 0; q < 4; q++) {
                    short8_t o;
#pragma unroll
                    for (int x = 0; x < 8; x++) o[x] = (short)f2bf(src[q * 8 + x]);
                    *(short8_t*)&Al[row * 72 + half * 32 + q * 8] = o;
                }
            } else {
                short8_t z = {0, 0, 0, 0, 0, 0, 0, 0};
#pragma unroll
                for (int q = 0; q < 4; q++)
                    *(short8_t*)&Al[row * 72 + half * 32 + q * 8] = z;
            }
        }
        // ---- stage B tile ----
        if constexpr (MODE == 0) {
            const unsigned short* src = Bbf + (size_t)(n0 + row) * KTOT + kbase;
#pragma unroll
            for (int q = 0; q < 4; q++)
                *(short8_t*)&Bl[row * 72 + half * 32 + q * 8] = *(const short8_t*)(src + q * 8);
        } else {
            // decode segmented HS: tile tokens = t in {2bn,2bn+1} x 64 batches; k-chunk = seg kt
            int t0 = bn * 2;
            int tt = tid >> 7, gg = (tid >> 4) & 7, dq = tid & 15;
#pragma unroll
            for (int dd = 0; dd < 4; dd++) {
                int d = dq * 4 + dd;
                uint4 vv = *(const uint4*)((const char*)Bbf +
                    ((((size_t)(t0 + tt) * 8 + gg) * 8 + kt) * 1024 + (size_t)d * 16));
#pragma unroll
                for (int lb = 0; lb < 8; lb++) {
                    unsigned u = vv[lb >> 1];
                    Bl[(tt * 64 + gg * 8 + lb) * 72 + d] =
                        (unsigned short)((lb & 1) ? (u >> 16) : (u & 0xFFFFu));
                }
            }
        }
        __syncthreads();
#pragma unroll
        for (int kk2 = 0; kk2 < 2; kk2++) {
            short8_t af[4], bfv[4];
#pragma unroll
            for (int i = 0; i < 4; i++)
                af[i] = *(const short8_t*)&Al[(wr * 64 + i * 16 + (l & 15)) * 72 + kk2 * 32 + (l >> 4) * 8];
#pragma unroll
            for (int j = 0; j < 4; j++)
                bfv[j] = *(const short8_t*)&Bl[(wc * 64 + j * 16 + (l & 15)) * 72 + kk2 * 32 + (l >> 4) * 8];
#pragma unroll
            for (int i = 0; i < 4; i++)
#pragma unroll
                for (int j = 0; j < 4; j++)
                    acc[i][j] = __builtin_amdgcn_mfma_f32_16x16x32_bf16(af[i], bfv[j], acc[i][j], 0, 0, 0);
        }
        __syncthreads();
    }
#pragma unroll
    for (int i = 0; i < 4; i++)
#pragma unroll
        for (int j = 0; j < 4; j++)
#pragma unroll
            for (int r = 0; r < 4; r++) {
                int m = m0 + wr * 64 + i * 16 + (l >> 4) * 4 + r;
                int n = n0 + wc * 64 + j * 16 + (l & 15);
                float v = acc[i][j][r];
                if constexpr (MODE == 0) {
                    int tt = n >> 6, gg = (n >> 3) & 7, lb = n & 7;
                    Cbf[((size_t)(gg * 2048 + m)) * 1600 + tt * 8 + lb] = f2bf(v);
                } else {
                    if (m < NLAB) {
                        int b = n & 63, s = n >> 6;
                        Cf32[((size_t)b * SEQ + s) * NLAB + m] = v + bias[m];
                    }
                }
            }
}

// ---------------- K4: persistent LSTM, 64 blocks x 512 threads, MFMA recurrence ----------
// block: g = bid&7 (8 batches), j = bid>>3 (h-dims [j*64, j*64+64) = 256 gate rows).
// W_hh rows pre-packed as MFMA A-fragments in VGPRs (128/lane).
__global__ __launch_bounds__(512, 1) void lstm_k(const float* __restrict__ Whh,
                                                 const float* __restrict__ bvec,
                                                 const unsigned short* __restrict__ X,
                                                 unsigned short* __restrict__ HS,
                                                 unsigned* __restrict__ flags) {
    const int g = blockIdx.x & 7;
    const int j = blockIdx.x >> 3;
    const int tid = threadIdx.x;
    const int w = tid >> 6, l = tid & 63;

    __shared__ unsigned short hB[16][520];   // [batch(8 real+8 zero-pad)][k=512]
    __shared__ float gates_l[256][10];       // [local gate row][batch], padded
    __shared__ float bias_s[256];

    // ---- pack W_hh into MFMA A-fragments: wave w -> gate q=w>>1, dims (w&1)*32.. ----
    const int q = w >> 1, ebase = (w & 1) * 32;
    short8_t wreg[2][16];
#pragma unroll
    for (int mt = 0; mt < 2; mt++)
#pragma unroll
        for (int ks = 0; ks < 16; ks++) {
            int gr = q * 512 + j * 64 + ebase + mt * 16 + (l & 15);
            const float* wp = Whh + (size_t)gr * HID + ks * 32 + (l >> 4) * 8;
            float4 f0 = *(const float4*)wp;
            float4 f1 = *(const float4*)(wp + 4);
            short8_t o;
            o[0] = (short)f2bf(f0.x); o[1] = (short)f2bf(f0.y);
            o[2] = (short)f2bf(f0.z); o[3] = (short)f2bf(f0.w);
            o[4] = (short)f2bf(f1.x); o[5] = (short)f2bf(f1.y);
            o[6] = (short)f2bf(f1.z); o[7] = (short)f2bf(f1.w);
            wreg[mt][ks] = o;
        }
    for (int idx = tid; idx < 16 * 520; idx += 512) ((unsigned short*)hB)[idx] = 0;
    if (tid < 256) bias_s[tid] = bvec[(tid >> 6) * 512 + j * 64 + (tid & 63)];
    __syncthreads();

    unsigned* gfl = flags + g * 32;          // 8 flags (16B apart) in one 128B line
    unsigned* HSu = (unsigned*)HS;
    const int e = tid >> 3, lb = tid & 7;    // elementwise role: dim e, batch lb
    float cpriv = 0.f;

    for (int t = 0; t < SEQ; t++) {
        // ---- prefetch X gates (plain cached loads; t-contiguous lines) ----
        float xv[4];
#pragma unroll
        for (int q2 = 0; q2 < 4; q2++)
            xv[q2] = bf2f(X[((size_t)(g * 2048 + q2 * 512 + j * 64 + e)) * 1600 + t * 8 + lb]);

        // ---- phase 1: wait + stage h_{t-1} ----
        if (t > 0) {
            if (w == 0) {
                unsigned v = ld1_sc1(&gfl[(l & 7) * 4]);
                while (!__all((int)(v >= (unsigned)t))) {
                    __builtin_amdgcn_s_sleep(2);
                    v = ld1_sc1(&gfl[(l & 7) * 4]);
                }
            }
            __syncthreads();
            // 8KB group h: thread reads 16B = 8 batches of dim k=tid
            const unsigned* hsrc = HSu + ((size_t)(t - 1) * 8 + g) * 2048 + tid * 4;
            uint4 va;
            ld4_sc1(hsrc, va);
#pragma unroll
            for (int i = 0; i < 4; i++) {
                unsigned u = va[i];
                hB[2 * i][tid] = (unsigned short)(u & 0xFFFFu);
                hB[2 * i + 1][tid] = (unsigned short)(u >> 16);
            }
        }
        __syncthreads();

        // ---- phase 2: MFMA  gates = W_hh(block rows) . h  (32 MFMA/wave) ----
        f32x4_t a0 = {0.f, 0.f, 0.f, 0.f}, a1 = {0.f, 0.f, 0.f, 0.f};
#pragma unroll
        for (int ks = 0; ks < 16; ks++) {
            short8_t bf = *(const short8_t*)&hB[l & 15][ks * 32 + (l >> 4) * 8];
            a0 = __builtin_amdgcn_mfma_f32_16x16x32_bf16(wreg[0][ks], bf, a0, 0, 0, 0);
            a1 = __builtin_amdgcn_mfma_f32_16x16x32_bf16(wreg[1][ks], bf, a1, 0, 0, 0);
        }
        if ((l & 15) < 8) {
            int rb = w * 32 + (l >> 4) * 4;
#pragma unroll
            for (int r = 0; r < 4; r++) gates_l[rb + r][l & 7] = a0[r];
#pragma unroll
            for (int r = 0; r < 4; r++) gates_l[rb + 16 + r][l & 7] = a1[r];
        }
        __syncthreads();

        // ---- phase 3: elementwise LSTM cell (all 512: dim e x batch lb) ----
        float pre[4];
#pragma unroll
        for (int q2 = 0; q2 < 4; q2++)
            pre[q2] = gates_l[q2 * 64 + e][lb] + bias_s[q2 * 64 + e] + xv[q2];
        float ig = sigm(pre[0]);
        float fg = sigm(pre[1]);
        float gg = tanhfast(pre[2]);
        float og = sigm(pre[3]);
        float c = fg * cpriv + ig * gg;
        cpriv = c;
        float h = og * tanhfast(c);
        // pack with neighbor (lb^1), contiguous 1KB segment store
        unsigned short hb = f2bf(h);
        unsigned short hb1 = (unsigned short)__shfl_xor((int)hb, 1);
        if ((tid & 1) == 0) {
            unsigned pk = (unsigned)hb | ((unsigned)hb1 << 16);
            unsigned* seg = HSu + ((size_t)t * 8 + g) * 2048 + j * 256;
            st1_sc1(&seg[tid >> 1], pk);
        }
        asm volatile("s_waitcnt vmcnt(0)" ::: "memory");
        __syncthreads();
        if (tid == 0) st1_sc1(&gfl[j * 4], (unsigned)(t + 1));
    }
}

// ---------------- K6: CRF forward + scores, one block per batch ----------------
__global__ __launch_bounds__(320) void crf_k(const float* __restrict__ F,
                                             const float* __restrict__ trans,
                                             const int* __restrict__ labels,
                                             const int* __restrict__ lengths,
                                             float* __restrict__ out) {
    const int b = blockIdx.x;
    const int tid = threadIdx.x;
    __shared__ float tl[NLAB * NLAB];
    __shared__ float alpha[2][68];
    __shared__ float fbuf[68];
    __shared__ float red[8];
    __shared__ float norm_s;
    for (int i = tid; i < NLAB * NLAB; i += 320) tl[i] = trans[i];
    const int L = lengths[b];
    const int ii = tid >> 2, jq = tid & 3;
    const int j0 = (jq < 2) ? jq * 17 : 34 + (jq - 2) * 16;
    const int jn = (jq < 2) ? 17 : 16;
    if (tid < NLAB) alpha[0][tid] = (tid == START_L) ? 0.f : -10000.f;
    __syncthreads();
    int p = 0;
    for (int t = 0; t < L; t++) {
        if (tid < NLAB) fbuf[tid] = F[((size_t)b * SEQ + t) * NLAB + tid];
        __syncthreads();
        if (ii < NLAB) {
            float v[17];
            float m = -3.0e38f;
#pragma unroll
            for (int u = 0; u < 17; u++) {
                float x = (u < jn) ? tl[ii * NLAB + j0 + u] + alpha[p][j0 + u] : -3.0e38f;
                v[u] = x;
                m = fmaxf(m, x);
            }
            m = fmaxf(m, __shfl_xor(m, 1));
            m = fmaxf(m, __shfl_xor(m, 2));
            float s = 0.f;
#pragma unroll
            for (int u = 0; u < 17; u++) s += __expf(v[u] - m);
            s += __shfl_xor(s, 1);
            s += __shfl_xor(s, 2);
            if (jq == 0) alpha[p ^ 1][ii] = m + __logf(s) + fbuf[ii];
        }
        __syncthreads();
        p ^= 1;
    }
    if (tid < 64) {
        float v0 = alpha[p][tid] + tl[STOP_L * NLAB + tid];
        float v1 = (tid + 64 < NLAB) ? alpha[p][tid + 64] + tl[STOP_L * NLAB + tid + 64] : -3.0e38f;
        float m = fmaxf(v0, v1);
#pragma unroll
        for (int off = 1; off < 64; off <<= 1) m = fmaxf(m, __shfl_xor(m, off));
        float s = __expf(v0 - m) + ((tid + 64 < NLAB) ? __expf(v1 - m) : 0.f);
#pragma unroll
        for (int off = 1; off < 64; off <<= 1) s += __shfl_xor(s, off);
        if (tid == 0) norm_s = m + __logf(s);
    }
    float local = 0.f;
    const int* lab = labels + (size_t)b * SEQ;
    for (int k = tid; k < L; k += 320) {
        int lk = lab[k];
        int prev = (k == 0) ? START_L : lab[k - 1];
        local += tl[lk * NLAB + prev] + F[((size_t)b * SEQ + k) * NLAB + lk];
    }
    if (tid == 0) local += tl[STOP_L * NLAB + lab[L - 1]];
#pragma unroll
    for (int off = 1; off < 64; off <<= 1) local += __shfl_xor(local, off);
    if ((tid & 63) == 0) red[tid >> 6] = local;
    __syncthreads();
    if (tid == 0) {
        float tot = red[0] + red[1] + red[2] + red[3] + red[4];
        out[b] = norm_s - tot;
    }
}

// ---------------- launch ----------------
extern "C" void kernel_launch(void* const* d_in, const int* in_sizes, int n_in,
                              void* d_out, int out_size, void* d_ws, size_t ws_size,
                              hipStream_t stream) {
    const int* data = (const int*)d_in[0];
    const int* lengths = (const int*)d_in[1];
    const int* labels = (const int*)d_in[2];
    const float* emb = (const float*)d_in[3];
    const float* W_ih = (const float*)d_in[4];
    const float* W_hh = (const float*)d_in[5];
    const float* bvec = (const float*)d_in[6];
    const float* W_fc = (const float*)d_in[7];
    const float* b_fc = (const float*)d_in[8];
    const float* trans = (const float*)d_in[9];
    float* out = (float*)d_out;

    // workspace layout (bytes)
    const size_t oA = 0;                 // Aemb bf16 [12800][320]   8,192,000
    const size_t oW = 8192000;           // Wihb bf16 [2048][320]    1,310,720
    const size_t oX = 9502720;           // Xr bf16 [8][2048][200][8] 52,428,800
    const size_t oHS = 61931520;         // HS segmented bf16       13,107,200
    const size_t oF = 75038720;          // F fp32 [64][200][66]     3,379,200
    const size_t oC = 78417920;          // flags [8][32] uint           1,024
    const size_t need = 78418944;
    if (ws_size < need) return;

    char* w = (char*)d_ws;
    unsigned short* A = (unsigned short*)(w + oA);
    unsigned short* Wb = (unsigned short*)(w + oW);
    unsigned short* X = (unsigned short*)(w + oX);
    unsigned short* HS = (unsigned short*)(w + oHS);
    float* F = (float*)(w + oF);
    unsigned* flags = (unsigned*)(w + oC);

    hipMemsetAsync(flags, 0, 1024, stream);
    embed_k<<<3200, 256, 0, stream>>>(data, emb, A);
    convw_k<<<2560, 256, 0, stream>>>(W_ih, Wb);
    gemm_k<0><<<1600, 256, 0, stream>>>(Wb, nullptr, A, X, nullptr, nullptr);
    lstm_k<<<64, 512, 0, stream>>>(W_hh, bvec, X, HS, flags);
    gemm_k<1><<<100, 256, 0, stream>>>(nullptr, W_fc, HS, nullptr, F, b_fc);
    crf_k<<<64, 320, 0, stream>>>(F, trans, labels, lengths, out);
}